// Round 5
// baseline (464.837 us; speedup 1.0000x reference)
//
#include <hip/hip_runtime.h>
#include <hip/hip_bf16.h>

// Problem constants (from reference)
#define MM 5000      // matches
#define LC 4800      // coarse cells
// feat_f: [4][128][240][320], feat_c: [4][4800][256]

typedef __attribute__((ext_vector_type(8))) short bf16x8;
typedef __attribute__((ext_vector_type(4))) float f32x4;

__device__ __forceinline__ unsigned short f2bf(float f) {
    unsigned int u = __builtin_bit_cast(unsigned int, f);
    u += 0x7fffu + ((u >> 16) & 1u);   // RNE
    return (unsigned short)(u >> 16);
}

// K0: Wcomb = merge_w[:,128:] @ down_proj_w  -> bf16 [128][256]
//     W1    = merge_w[:,:128]                -> bf16 [128][128]
//     bvec  = merge_b + down_proj_b @ merge_w[:,128:].T   (fp32 [128])
__global__ void k0_prep(const float* __restrict__ merge_w,
                        const float* __restrict__ down_w,
                        const float* __restrict__ merge_b,
                        const float* __restrict__ down_b,
                        unsigned short* __restrict__ w1_bf,
                        unsigned short* __restrict__ wc_bf,
                        float* __restrict__ bvec)
{
    int o = blockIdx.x * 256 + threadIdx.x;        // 128 blocks -> o in [0,32768)
    int cf = o >> 8, cc = o & 255;
    const float* w2row = merge_w + cf * 256 + 128; // W2[cf][:]
    float acc = 0.f;
    #pragma unroll 4
    for (int j = 0; j < 128; ++j)
        acc = fmaf(w2row[j], down_w[j * 256 + cc], acc);
    wc_bf[o] = f2bf(acc);
    if (o < 16384)
        w1_bf[o] = f2bf(merge_w[(o >> 7) * 256 + (o & 127)]);
    if (o < 128) {
        const float* w2r = merge_w + o * 256 + 128;
        float a = merge_b[o];
        for (int j = 0; j < 128; ++j) a = fmaf(down_b[j], w2r[j], a);
        bvec[o] = a;
    }
}

// K1: bias2[sm][cf] = feat_c_row(sm) @ Wcomb[cf][:] + bvec[cf]; sm in [0,10000)
// block = 32 sm rows x 128 cf, K=256, bf16 MFMA 16x16x32.
// Block 313 (extra) is the fused counting sort (key=(side,b,l)>>3):
// LDS histogram + scan + scatter -> perm. Saves a standalone launch.
__global__ void __launch_bounds__(256) k1_bias(
    const float* __restrict__ feat_c0, const float* __restrict__ feat_c1,
    const int* __restrict__ b_ids, const int* __restrict__ i_ids,
    const int* __restrict__ j_ids,
    const unsigned short* __restrict__ wc_bf, const float* __restrict__ bvec,
    float* __restrict__ bias2, int* __restrict__ perm)
{
    __shared__ unsigned smbuf_u[5056];   // 20224 B: max(sorter 20224, ac 16896)
    const int t = threadIdx.x;

    if (blockIdx.x == (2 * MM + 31) / 32) {        // sorter block
        unsigned* hist = smbuf_u;                  // 4800
        unsigned* part = smbuf_u + 4800;           // 256
        for (int i = t; i < 4800; i += 256) hist[i] = 0u;
        __syncthreads();
        for (int s = t; s < 2 * MM; s += 256) {
            int side = s >= MM; int mm = s - side * MM;
            int l = side ? j_ids[mm] : i_ids[mm];
            atomicAdd(&hist[((unsigned)(side * (4 * LC) + b_ids[mm] * LC + l)) >> 3], 1u);
        }
        __syncthreads();
        unsigned loc[19], sum = 0u;
        const int s0i = t * 19;                    // 256*19 = 4864 >= 4800
        #pragma unroll
        for (int i = 0; i < 19; ++i) {
            int idx = s0i + i;
            unsigned v = (idx < 4800) ? hist[idx] : 0u;
            loc[i] = sum; sum += v;
        }
        part[t] = sum;
        __syncthreads();
        for (int off = 1; off < 256; off <<= 1) {
            unsigned v = (t >= off) ? part[t - off] : 0u;
            __syncthreads();
            part[t] += v;
            __syncthreads();
        }
        unsigned base = (t == 0) ? 0u : part[t - 1];
        #pragma unroll
        for (int i = 0; i < 19; ++i) {
            int idx = s0i + i;
            if (idx < 4800) hist[idx] = base + loc[i];
        }
        __syncthreads();
        for (int s = t; s < 2 * MM; s += 256) {
            int side = s >= MM; int mm = s - side * MM;
            int l = side ? j_ids[mm] : i_ids[mm];
            unsigned pos = atomicAdd(&hist[((unsigned)(side * (4 * LC) + b_ids[mm] * LC + l)) >> 3], 1u);
            perm[pos] = s;
        }
        return;
    }

    unsigned short (*ac)[264] = (unsigned short (*)[264])smbuf_u;   // 32 x 264
    const int base = blockIdx.x * 32;
    {
        int row = t >> 3;
        int seg = (t & 7) * 32;
        int sm = base + row; if (sm > 2 * MM - 1) sm = 2 * MM - 1;
        int side = sm >= MM;
        int mm = sm - side * MM;
        int id = side ? j_ids[mm] : i_ids[mm];
        int b  = b_ids[mm];
        const float* src = (side ? feat_c1 : feat_c0)
                           + (size_t)(b * LC + id) * 256 + seg;
        const float4* s4 = (const float4*)src;
        #pragma unroll
        for (int i = 0; i < 8; ++i) {
            float4 v = s4[i];
            ushort4 u; u.x = f2bf(v.x); u.y = f2bf(v.y); u.z = f2bf(v.z); u.w = f2bf(v.w);
            *(ushort4*)&ac[row][seg + i * 4] = u;
        }
    }
    __syncthreads();
    const int lane = t & 63, wave = t >> 6;
    const int ln = lane & 15, q = lane >> 4;
    const int n0 = wave * 32;
    f32x4 acc[2][2] = {};
    #pragma unroll
    for (int k0 = 0; k0 < 8; ++k0) {
        bf16x8 a0 = *(const bf16x8*)&ac[ln][k0 * 32 + q * 8];
        bf16x8 a1 = *(const bf16x8*)&ac[16 + ln][k0 * 32 + q * 8];
        bf16x8 b0 = *(const bf16x8*)(wc_bf + (size_t)(n0 + ln) * 256 + k0 * 32 + q * 8);
        bf16x8 b1 = *(const bf16x8*)(wc_bf + (size_t)(n0 + 16 + ln) * 256 + k0 * 32 + q * 8);
        acc[0][0] = __builtin_amdgcn_mfma_f32_16x16x32_bf16(a0, b0, acc[0][0], 0, 0, 0);
        acc[0][1] = __builtin_amdgcn_mfma_f32_16x16x32_bf16(a0, b1, acc[0][1], 0, 0, 0);
        acc[1][0] = __builtin_amdgcn_mfma_f32_16x16x32_bf16(a1, b0, acc[1][0], 0, 0, 0);
        acc[1][1] = __builtin_amdgcn_mfma_f32_16x16x32_bf16(a1, b1, acc[1][1], 0, 0, 0);
    }
    #pragma unroll
    for (int mt = 0; mt < 2; ++mt)
      #pragma unroll
      for (int nt = 0; nt < 2; ++nt) {
        int cf = n0 + nt * 16 + ln;
        float bv = bvec[cf];
        #pragma unroll
        for (int r = 0; r < 4; ++r) {
            int sm = base + mt * 16 + q * 4 + r;
            if (sm < 2 * MM)
                bias2[(size_t)sm * 128 + cf] = acc[mt][nt][r] + bv;
        }
      }
}

// ---- K2 helpers ----
struct GP { int split, base0, base1, khm20, khm21, kwm20, kwm21, p0; };

__device__ __forceinline__ GP decodeParams(int l) {
    GP g;
    unsigned fbase = (unsigned)l * 3200u;
    unsigned cc0 = fbase / 4800u;
    unsigned p0 = fbase - cc0 * 4800u;            // in {0,1600,3200}
    unsigned rem = 4800u - p0;
    g.split = (int)(rem < 3200u ? rem : 3200u);
    g.p0 = (int)p0;
    unsigned cc1 = cc0 + 1u;
    int ch0 = (int)(cc0 / 25u), k50 = (int)(cc0 - (unsigned)ch0 * 25u);
    int kh0 = k50 / 5, kw0 = k50 - kh0 * 5;
    int ch1 = (int)(cc1 / 25u), k51 = (int)(cc1 - (unsigned)ch1 * 25u);
    int kh1 = k51 / 5, kw1 = k51 - kh1 * 5;
    g.base0 = ch0 * 76800; g.base1 = ch1 * 76800;
    g.khm20 = kh0 - 2; g.khm21 = kh1 - 2;
    g.kwm20 = kw0 - 2; g.kwm21 = kw1 - 2;
    return g;
}

__device__ __forceinline__ unsigned gatherIssue(const GP g, const float* __restrict__ fn,
                                                int t, float val[13]) {
    unsigned vmask = 0;
    #pragma unroll
    for (int it = 0; it < 13; ++it) {
        int idx = t + it * 256;
        idx = idx < 3199 ? idx : 3199;            // clamp: dup load, never written
        const int selB = idx >= g.split;
        const unsigned p = (unsigned)(selB ? idx - g.split : idx + g.p0);
        const int ho = (int)(p / 80u);            // single magic-div per element
        const int wo = (int)p - ho * 80;
        const int r   = 4 * ho + (selB ? g.khm21 : g.khm20);   // < 240 always
        const int col = 4 * wo + (selB ? g.kwm21 : g.kwm20);   // < 320 always
        const int ok = (r >= 0) & (col >= 0);
        int off = (selB ? g.base1 : g.base0) + r * 320 + col;
        off = ok ? off : 0;                       // clamp invalid to a safe addr
        val[it] = fn[off];
        vmask |= (unsigned)ok << it;
    }
    return vmask;
}

__device__ __forceinline__ void cvtToLds(unsigned short (*fw)[136], int t,
                                         const float val[13], unsigned vmask) {
    #pragma unroll
    for (int it = 0; it < 13; ++it) {
        int idx = t + it * 256;
        if (it < 12 || idx < 3200) {
            float v = ((vmask >> it) & 1u) ? val[it] : 0.f;
            fw[idx >> 7][idx & 127] = f2bf(v);
        }
    }
}

__device__ __forceinline__ void mfma22(const unsigned short (*fw)[136],
                                       const bf16x8 (&bf)[2][4],
                                       int ln, int q, f32x4 (&acc)[2][2]) {
    #pragma unroll
    for (int k0 = 0; k0 < 4; ++k0) {
        bf16x8 a0 = *(const bf16x8*)&fw[ln][k0 * 32 + q * 8];
        bf16x8 a1 = *(const bf16x8*)&fw[16 + ln][k0 * 32 + q * 8];   // rows>=25 garbage: feeds unstored D rows
        acc[0][0] = __builtin_amdgcn_mfma_f32_16x16x32_bf16(a0, bf[0][k0], acc[0][0], 0, 0, 0);
        acc[0][1] = __builtin_amdgcn_mfma_f32_16x16x32_bf16(a0, bf[1][k0], acc[0][1], 0, 0, 0);
        acc[1][0] = __builtin_amdgcn_mfma_f32_16x16x32_bf16(a1, bf[0][k0], acc[1][0], 0, 0, 0);
        acc[1][1] = __builtin_amdgcn_mfma_f32_16x16x32_bf16(a1, bf[1][k0], acc[1][1], 0, 0, 0);
    }
}

__device__ __forceinline__ void storeD(const f32x4 (&acc)[2][2], const float* brow,
                                       float* __restrict__ out, int bx,
                                       int n0, int ln, int q) {
    float* ob = out + (size_t)bx * 3200;
    #pragma unroll
    for (int nt = 0; nt < 2; ++nt) {
        int cf = n0 + nt * 16 + ln;
        float bv = brow[cf];
        #pragma unroll
        for (int mt = 0; mt < 2; ++mt)
          #pragma unroll
          for (int r = 0; r < 4; ++r) {
            int w = mt * 16 + q * 4 + r;
            if (w < 25)
                ob[w * 128 + cf] = acc[mt][nt][r] + bv;
          }
    }
}

// K2: TWO consecutive sorted match-sides per block, software-pipelined:
// tile1's gather loads are issued BEFORE tile0's MFMA+epilogue so the CU
// always has a 13-deep load batch in flight (covers the MFMA/store/barrier
// phase gaps that capped the per-CU line-fill rate at ~65% of streaming).
// In-pair dedup: equal (side,b,l) -> compute once, store twice.
__global__ void __launch_bounds__(256, 6) k2_main(
    const float* __restrict__ feat_f0, const float* __restrict__ feat_f1,
    const int* __restrict__ b_ids, const int* __restrict__ i_ids,
    const int* __restrict__ j_ids,
    const unsigned short* __restrict__ w1_bf, const float* __restrict__ bias2,
    const int* __restrict__ perm,
    float* __restrict__ out)
{
    __shared__ unsigned short fw0[32][136];   // 8704 B
    __shared__ unsigned short fw1[32][136];   // 8704 B
    __shared__ float brow0[128], brow1[128];
    const int t = threadIdx.x;
    const int bid = blockIdx.x;                    // [0,5000), 5000 = 8*625
    const int qq = (bid & 7) * 625 + (bid >> 3);   // XCD-chunk swizzle
    const int s0 = perm[2 * qq], s1 = perm[2 * qq + 1];

    const int side0 = s0 >= MM, m0 = s0 - side0 * MM;
    const int l0 = side0 ? j_ids[m0] : i_ids[m0];
    const int n0b = b_ids[m0];
    const int side1 = s1 >= MM, m1 = s1 - side1 * MM;
    const int l1 = side1 ? j_ids[m1] : i_ids[m1];
    const int n1b = b_ids[m1];
    const float* fn0 = (side0 ? feat_f1 : feat_f0) + (size_t)n0b * (128 * 240 * 320);
    const float* fn1 = (side1 ? feat_f1 : feat_f0) + (size_t)n1b * (128 * 240 * 320);
    const bool dup = (l0 == l1) && (n0b == n1b) && (side0 == side1);

    if (t < 128) {
        brow0[t] = bias2[(size_t)s0 * 128 + t];
        brow1[t] = bias2[(size_t)s1 * 128 + t];
    }

    // tile0 gather issue
    GP g0 = decodeParams(l0);
    float val[13];
    unsigned vm = gatherIssue(g0, fn0, t, val);

    // W1 B-fragments (32 KB table, L2-hot)
    const int lane = t & 63, wave = t >> 6;
    const int ln = lane & 15, q = lane >> 4;
    const int n0 = wave * 32;
    bf16x8 bf[2][4];
    #pragma unroll
    for (int nt = 0; nt < 2; ++nt)
      #pragma unroll
      for (int k0 = 0; k0 < 4; ++k0)
        bf[nt][k0] = *(const bf16x8*)(w1_bf + (n0 + nt * 16 + ln) * 128 + k0 * 32 + q * 8);

    cvtToLds(fw0, t, val, vm);
    __syncthreads();

    // tile1 gather issue — in flight during tile0 MFMA + epilogue
    unsigned vm1 = 0;
    if (!dup) {
        GP g1 = decodeParams(l1);
        vm1 = gatherIssue(g1, fn1, t, val);
    }

    f32x4 acc[2][2] = {};
    mfma22(fw0, bf, ln, q, acc);
    storeD(acc, brow0, out, s0, n0, ln, q);
    if (dup) {
        storeD(acc, brow1, out, s1, n0, ln, q);   // identical D by construction
        return;
    }

    cvtToLds(fw1, t, val, vm1);
    __syncthreads();

    f32x4 acc1[2][2] = {};
    mfma22(fw1, bf, ln, q, acc1);
    storeD(acc1, brow1, out, s1, n0, ln, q);
}

extern "C" void kernel_launch(void* const* d_in, const int* in_sizes, int n_in,
                              void* d_out, int out_size, void* d_ws, size_t ws_size,
                              hipStream_t stream) {
    const float* feat_f0 = (const float*)d_in[0];
    const float* feat_f1 = (const float*)d_in[1];
    const float* feat_c0 = (const float*)d_in[2];
    const float* feat_c1 = (const float*)d_in[3];
    const int*   b_ids   = (const int*)d_in[4];
    const int*   i_ids   = (const int*)d_in[5];
    const int*   j_ids   = (const int*)d_in[6];
    const float* down_w  = (const float*)d_in[7];
    const float* down_b  = (const float*)d_in[8];
    const float* merge_w = (const float*)d_in[9];
    const float* merge_b = (const float*)d_in[10];
    float* out = (float*)d_out;

    char* ws = (char*)d_ws;
    unsigned short* w1_bf = (unsigned short*)(ws);            // 32 KB
    unsigned short* wc_bf = (unsigned short*)(ws + 32768);    // 64 KB
    float* bvec  = (float*)(ws + 98304);                      // 512 B
    float* bias2 = (float*)(ws + 98816);                      // 10000*128*4 = 5.12 MB
    int*   perm  = (int*)(ws + 5218816);                      // 40 KB

    hipLaunchKernelGGL(k0_prep, dim3(128), dim3(256), 0, stream,
                       merge_w, down_w, merge_b, down_b, w1_bf, wc_bf, bvec);
    hipLaunchKernelGGL(k1_bias, dim3((2 * MM + 31) / 32 + 1), dim3(256), 0, stream,
                       feat_c0, feat_c1, b_ids, i_ids, j_ids, wc_bf, bvec, bias2, perm);
    hipLaunchKernelGGL(k2_main, dim3(MM), dim3(256), 0, stream,
                       feat_f0, feat_f1, b_ids, i_ids, j_ids, w1_bf, bias2, perm, out);
}

// Round 6
// 419.861 us; speedup vs baseline: 1.1071x; 1.1071x over previous
//
#include <hip/hip_runtime.h>
#include <hip/hip_bf16.h>

// Problem constants (from reference)
#define MM 5000      // matches
#define LC 4800      // coarse cells
// feat_f: [4][128][240][320], feat_c: [4][4800][256]

typedef __attribute__((ext_vector_type(8))) short bf16x8;
typedef __attribute__((ext_vector_type(4))) float f32x4;

__device__ __forceinline__ unsigned short f2bf(float f) {
    unsigned int u = __builtin_bit_cast(unsigned int, f);
    u += 0x7fffu + ((u >> 16) & 1u);   // RNE
    return (unsigned short)(u >> 16);
}

// K0: Wcomb = merge_w[:,128:] @ down_proj_w  -> bf16 [128][256]
//     W1    = merge_w[:,:128]                -> bf16 [128][128]
//     bvec  = merge_b + down_proj_b @ merge_w[:,128:].T   (fp32 [128])
__global__ void k0_prep(const float* __restrict__ merge_w,
                        const float* __restrict__ down_w,
                        const float* __restrict__ merge_b,
                        const float* __restrict__ down_b,
                        unsigned short* __restrict__ w1_bf,
                        unsigned short* __restrict__ wc_bf,
                        float* __restrict__ bvec)
{
    int o = blockIdx.x * 256 + threadIdx.x;        // 128 blocks -> o in [0,32768)
    int cf = o >> 8, cc = o & 255;
    const float* w2row = merge_w + cf * 256 + 128; // W2[cf][:]
    float acc = 0.f;
    #pragma unroll 4
    for (int j = 0; j < 128; ++j)
        acc = fmaf(w2row[j], down_w[j * 256 + cc], acc);
    wc_bf[o] = f2bf(acc);
    if (o < 16384)
        w1_bf[o] = f2bf(merge_w[(o >> 7) * 256 + (o & 127)]);
    if (o < 128) {
        const float* w2r = merge_w + o * 256 + 128;
        float a = merge_b[o];
        for (int j = 0; j < 128; ++j) a = fmaf(down_b[j], w2r[j], a);
        bvec[o] = a;
    }
}

// K1: bias2[sm][cf] = feat_c_row(sm) @ Wcomb[cf][:] + bvec[cf]; sm in [0,10000)
// block = 32 sm rows x 128 cf, K=256, bf16 MFMA 16x16x32.
// Block 313 (extra) is the fused counting sort (key=(side,b,l)>>3):
// LDS histogram + scan + scatter -> perm. Saves a standalone launch.
__global__ void __launch_bounds__(256) k1_bias(
    const float* __restrict__ feat_c0, const float* __restrict__ feat_c1,
    const int* __restrict__ b_ids, const int* __restrict__ i_ids,
    const int* __restrict__ j_ids,
    const unsigned short* __restrict__ wc_bf, const float* __restrict__ bvec,
    float* __restrict__ bias2, int* __restrict__ perm)
{
    __shared__ unsigned smbuf_u[5056];   // 20224 B: max(sorter 20224, ac 16896)
    const int t = threadIdx.x;

    if (blockIdx.x == (2 * MM + 31) / 32) {        // sorter block
        unsigned* hist = smbuf_u;                  // 4800
        unsigned* part = smbuf_u + 4800;           // 256
        for (int i = t; i < 4800; i += 256) hist[i] = 0u;
        __syncthreads();
        for (int s = t; s < 2 * MM; s += 256) {
            int side = s >= MM; int mm = s - side * MM;
            int l = side ? j_ids[mm] : i_ids[mm];
            atomicAdd(&hist[((unsigned)(side * (4 * LC) + b_ids[mm] * LC + l)) >> 3], 1u);
        }
        __syncthreads();
        unsigned loc[19], sum = 0u;
        const int s0i = t * 19;                    // 256*19 = 4864 >= 4800
        #pragma unroll
        for (int i = 0; i < 19; ++i) {
            int idx = s0i + i;
            unsigned v = (idx < 4800) ? hist[idx] : 0u;
            loc[i] = sum; sum += v;
        }
        part[t] = sum;
        __syncthreads();
        for (int off = 1; off < 256; off <<= 1) {
            unsigned v = (t >= off) ? part[t - off] : 0u;
            __syncthreads();
            part[t] += v;
            __syncthreads();
        }
        unsigned base = (t == 0) ? 0u : part[t - 1];
        #pragma unroll
        for (int i = 0; i < 19; ++i) {
            int idx = s0i + i;
            if (idx < 4800) hist[idx] = base + loc[i];
        }
        __syncthreads();
        for (int s = t; s < 2 * MM; s += 256) {
            int side = s >= MM; int mm = s - side * MM;
            int l = side ? j_ids[mm] : i_ids[mm];
            unsigned pos = atomicAdd(&hist[((unsigned)(side * (4 * LC) + b_ids[mm] * LC + l)) >> 3], 1u);
            perm[pos] = s;
        }
        return;
    }

    unsigned short (*ac)[264] = (unsigned short (*)[264])smbuf_u;   // 32 x 264
    const int base = blockIdx.x * 32;
    {
        int row = t >> 3;
        int seg = (t & 7) * 32;
        int sm = base + row; if (sm > 2 * MM - 1) sm = 2 * MM - 1;
        int side = sm >= MM;
        int mm = sm - side * MM;
        int id = side ? j_ids[mm] : i_ids[mm];
        int b  = b_ids[mm];
        const float* src = (side ? feat_c1 : feat_c0)
                           + (size_t)(b * LC + id) * 256 + seg;
        const float4* s4 = (const float4*)src;
        #pragma unroll
        for (int i = 0; i < 8; ++i) {
            float4 v = s4[i];
            ushort4 u; u.x = f2bf(v.x); u.y = f2bf(v.y); u.z = f2bf(v.z); u.w = f2bf(v.w);
            *(ushort4*)&ac[row][seg + i * 4] = u;
        }
    }
    __syncthreads();
    const int lane = t & 63, wave = t >> 6;
    const int ln = lane & 15, q = lane >> 4;
    const int n0 = wave * 32;
    f32x4 acc[2][2] = {};
    #pragma unroll
    for (int k0 = 0; k0 < 8; ++k0) {
        bf16x8 a0 = *(const bf16x8*)&ac[ln][k0 * 32 + q * 8];
        bf16x8 a1 = *(const bf16x8*)&ac[16 + ln][k0 * 32 + q * 8];
        bf16x8 b0 = *(const bf16x8*)(wc_bf + (size_t)(n0 + ln) * 256 + k0 * 32 + q * 8);
        bf16x8 b1 = *(const bf16x8*)(wc_bf + (size_t)(n0 + 16 + ln) * 256 + k0 * 32 + q * 8);
        acc[0][0] = __builtin_amdgcn_mfma_f32_16x16x32_bf16(a0, b0, acc[0][0], 0, 0, 0);
        acc[0][1] = __builtin_amdgcn_mfma_f32_16x16x32_bf16(a0, b1, acc[0][1], 0, 0, 0);
        acc[1][0] = __builtin_amdgcn_mfma_f32_16x16x32_bf16(a1, b0, acc[1][0], 0, 0, 0);
        acc[1][1] = __builtin_amdgcn_mfma_f32_16x16x32_bf16(a1, b1, acc[1][1], 0, 0, 0);
    }
    #pragma unroll
    for (int mt = 0; mt < 2; ++mt)
      #pragma unroll
      for (int nt = 0; nt < 2; ++nt) {
        int cf = n0 + nt * 16 + ln;
        float bv = bvec[cf];
        #pragma unroll
        for (int r = 0; r < 4; ++r) {
            int sm = base + mt * 16 + q * 4 + r;
            if (sm < 2 * MM)
                bias2[(size_t)sm * 128 + cf] = acc[mt][nt][r] + bv;
        }
      }
}

// ---- K2 macros (kept as macros, NOT functions: passing val[13] to a
// function decays to a pointer -> scratch allocation (round-5 bug:
// +260 MB scratch traffic). Everything stays in one body, statically
// indexed -> registers. ----
#define DECODE_GP(g, l)                                                    \
    { unsigned fbase = (unsigned)(l) * 3200u;                              \
      unsigned cc0 = fbase / 4800u;                                        \
      unsigned p0u = fbase - cc0 * 4800u;                                  \
      unsigned remu = 4800u - p0u;                                         \
      g.split = (int)(remu < 3200u ? remu : 3200u);                        \
      g.p0 = (int)p0u;                                                     \
      unsigned cc1 = cc0 + 1u;                                             \
      int ch0 = (int)(cc0 / 25u), k50 = (int)(cc0 - (unsigned)ch0 * 25u);  \
      int kh0 = k50 / 5, kw0 = k50 - kh0 * 5;                              \
      int ch1 = (int)(cc1 / 25u), k51 = (int)(cc1 - (unsigned)ch1 * 25u);  \
      int kh1 = k51 / 5, kw1 = k51 - kh1 * 5;                              \
      g.base0 = ch0 * 76800; g.base1 = ch1 * 76800;                        \
      g.khm20 = kh0 - 2; g.khm21 = kh1 - 2;                                \
      g.kwm20 = kw0 - 2; g.kwm21 = kw1 - 2; }

#define GATHER(g, fnp, VM)                                                 \
    { VM = 0;                                                              \
      _Pragma("unroll")                                                    \
      for (int it = 0; it < 13; ++it) {                                    \
        int idx = t + it * 256;                                            \
        idx = idx < 3199 ? idx : 3199;                                     \
        const int selB = idx >= g.split;                                   \
        const unsigned p = (unsigned)(selB ? idx - g.split : idx + g.p0);  \
        const int ho = (int)(p / 80u);                                     \
        const int wo = (int)p - ho * 80;                                   \
        const int r   = 4 * ho + (selB ? g.khm21 : g.khm20);               \
        const int col = 4 * wo + (selB ? g.kwm21 : g.kwm20);               \
        const int ok = (r >= 0) & (col >= 0);                              \
        int off = (selB ? g.base1 : g.base0) + r * 320 + col;              \
        off = ok ? off : 0;                                                \
        val[it] = fnp[off];                                                \
        VM |= (unsigned)ok << it; } }

#define CVT_TO_LDS(VM)                                                     \
    { _Pragma("unroll")                                                    \
      for (int it = 0; it < 13; ++it) {                                    \
        int idx = t + it * 256;                                            \
        if (it < 12 || idx < 3200) {                                       \
            float v = ((VM >> it) & 1u) ? val[it] : 0.f;                   \
            fw[idx >> 7][idx & 127] = f2bf(v); } } }

#define MFMA_TILE(acc)                                                     \
    { _Pragma("unroll")                                                    \
      for (int k0 = 0; k0 < 4; ++k0) {                                     \
        bf16x8 a0 = *(const bf16x8*)&fw[ln][k0 * 32 + q * 8];              \
        bf16x8 a1 = *(const bf16x8*)&fw[16 + ln][k0 * 32 + q * 8];         \
        acc[0][0] = __builtin_amdgcn_mfma_f32_16x16x32_bf16(a0, bf[0][k0], acc[0][0], 0, 0, 0); \
        acc[0][1] = __builtin_amdgcn_mfma_f32_16x16x32_bf16(a0, bf[1][k0], acc[0][1], 0, 0, 0); \
        acc[1][0] = __builtin_amdgcn_mfma_f32_16x16x32_bf16(a1, bf[0][k0], acc[1][0], 0, 0, 0); \
        acc[1][1] = __builtin_amdgcn_mfma_f32_16x16x32_bf16(a1, bf[1][k0], acc[1][1], 0, 0, 0); } }

#define DSTAGE(acc, browp)                                                 \
    { _Pragma("unroll")                                                    \
      for (int nt = 0; nt < 2; ++nt) {                                     \
        int cf = n0 + nt * 16 + ln;                                        \
        float bv = browp[cf];                                              \
        _Pragma("unroll")                                                  \
        for (int mt = 0; mt < 2; ++mt)                                     \
          _Pragma("unroll")                                                \
          for (int r = 0; r < 4; ++r) {                                    \
            int w = mt * 16 + q * 4 + r;                                   \
            if (w < 25) dls[w * 128 + cf] = acc[mt][nt][r] + bv; } } }

#define STREAMOUT(srow)                                                    \
    { float4* ob4 = (float4*)(out + (size_t)(srow) * 3200);                \
      const float4* d4 = (const float4*)dls;                               \
      _Pragma("unroll")                                                    \
      for (int i = t; i < 800; i += 256) ob4[i] = d4[i]; }

struct GP { int split, base0, base1, khm20, khm21, kwm20, kwm21, p0; };

// K2: TWO consecutive sorted match-sides per block, software-pipelined.
// tile1's 13 gather loads issue right after tile0's cvt barrier and drain
// only after tile0's MFMA + D-stage + stream-out -> the CU keeps loads in
// flight through the compute phases that previously had none.
// Epilogue = round-4 style: D staged in LDS, contiguous float4 stream-out.
// In-pair dedup: equal (side,b,l) -> compute once, store twice.
__global__ void __launch_bounds__(256, 5) k2_main(
    const float* __restrict__ feat_f0, const float* __restrict__ feat_f1,
    const int* __restrict__ b_ids, const int* __restrict__ i_ids,
    const int* __restrict__ j_ids,
    const unsigned short* __restrict__ w1_bf, const float* __restrict__ bias2,
    const int* __restrict__ perm,
    float* __restrict__ out)
{
    __shared__ char smem[12800 + 1024];
    unsigned short (*fw)[136] = (unsigned short (*)[136])smem;  // 32 x 136 (8704 B)
    float* dls   = (float*)smem;                                // 3200 f32 (aliases fw)
    float* brow0 = (float*)(smem + 12800);                      // 128 f32
    float* brow1 = brow0 + 128;                                 // 128 f32

    const int t = threadIdx.x;
    const int bid = blockIdx.x;                    // [0,5000), 5000 = 8*625
    const int qq = (bid & 7) * 625 + (bid >> 3);   // XCD-chunk swizzle
    const int s0 = perm[2 * qq], s1 = perm[2 * qq + 1];

    const int side0 = s0 >= MM, m0 = s0 - side0 * MM;
    const int l0 = side0 ? j_ids[m0] : i_ids[m0];
    const int nb0 = b_ids[m0];
    const int side1 = s1 >= MM, m1 = s1 - side1 * MM;
    const int l1 = side1 ? j_ids[m1] : i_ids[m1];
    const int nb1 = b_ids[m1];
    const float* fn0 = (side0 ? feat_f1 : feat_f0) + (size_t)nb0 * (128 * 240 * 320);
    const float* fn1 = (side1 ? feat_f1 : feat_f0) + (size_t)nb1 * (128 * 240 * 320);
    const bool dup = (l0 == l1) & (nb0 == nb1) & (side0 == side1);

    if (t < 128) {
        brow0[t] = bias2[(size_t)s0 * 128 + t];
        brow1[t] = bias2[(size_t)s1 * 128 + t];
    }

    // ---- tile0 gather issue ----
    GP g0; DECODE_GP(g0, l0);
    float val[13];
    unsigned vm0;
    GATHER(g0, fn0, vm0);

    // W1 B-fragments (32 KB table, L2-hot)
    const int lane = t & 63, wave = t >> 6;
    const int ln = lane & 15, q = lane >> 4;
    const int n0 = wave * 32;
    bf16x8 bf[2][4];
    #pragma unroll
    for (int nt = 0; nt < 2; ++nt)
      #pragma unroll
      for (int k0 = 0; k0 < 4; ++k0)
        bf[nt][k0] = *(const bf16x8*)(w1_bf + (n0 + nt * 16 + ln) * 128 + k0 * 32 + q * 8);

    CVT_TO_LDS(vm0);           // val dead after this; regs reused for tile1
    __syncthreads();

    // ---- tile1 gather issue: in flight across tile0 MFMA + epilogue ----
    unsigned vm1 = 0;
    if (!dup) {
        GP g1; DECODE_GP(g1, l1);
        GATHER(g1, fn1, vm1);
    }

    f32x4 acc[2][2] = {};
    MFMA_TILE(acc);
    __syncthreads();           // all fw reads done; LDS becomes D
    DSTAGE(acc, brow0);
    __syncthreads();
    STREAMOUT(s0);
    if (dup) {                 // identical coarse row -> identical D
        STREAMOUT(s1);
        return;
    }
    __syncthreads();           // dls reads done before fw overwrite

    CVT_TO_LDS(vm1);
    __syncthreads();
    f32x4 acc1[2][2] = {};
    MFMA_TILE(acc1);
    __syncthreads();
    DSTAGE(acc1, brow1);
    __syncthreads();
    STREAMOUT(s1);
}

extern "C" void kernel_launch(void* const* d_in, const int* in_sizes, int n_in,
                              void* d_out, int out_size, void* d_ws, size_t ws_size,
                              hipStream_t stream) {
    const float* feat_f0 = (const float*)d_in[0];
    const float* feat_f1 = (const float*)d_in[1];
    const float* feat_c0 = (const float*)d_in[2];
    const float* feat_c1 = (const float*)d_in[3];
    const int*   b_ids   = (const int*)d_in[4];
    const int*   i_ids   = (const int*)d_in[5];
    const int*   j_ids   = (const int*)d_in[6];
    const float* down_w  = (const float*)d_in[7];
    const float* down_b  = (const float*)d_in[8];
    const float* merge_w = (const float*)d_in[9];
    const float* merge_b = (const float*)d_in[10];
    float* out = (float*)d_out;

    char* ws = (char*)d_ws;
    unsigned short* w1_bf = (unsigned short*)(ws);            // 32 KB
    unsigned short* wc_bf = (unsigned short*)(ws + 32768);    // 64 KB
    float* bvec  = (float*)(ws + 98304);                      // 512 B
    float* bias2 = (float*)(ws + 98816);                      // 10000*128*4 = 5.12 MB
    int*   perm  = (int*)(ws + 5218816);                      // 40 KB

    hipLaunchKernelGGL(k0_prep, dim3(128), dim3(256), 0, stream,
                       merge_w, down_w, merge_b, down_b, w1_bf, wc_bf, bvec);
    hipLaunchKernelGGL(k1_bias, dim3((2 * MM + 31) / 32 + 1), dim3(256), 0, stream,
                       feat_c0, feat_c1, b_ids, i_ids, j_ids, wc_bf, bvec, bias2, perm);
    hipLaunchKernelGGL(k2_main, dim3(MM), dim3(256), 0, stream,
                       feat_f0, feat_f1, b_ids, i_ids, j_ids, w1_bf, bias2, perm, out);
}